// Round 1
// baseline (2874.910 us; speedup 1.0000x reference)
//
#include <hip/hip_runtime.h>

constexpr int B_ = 128, S_ = 25, NF_ = 196, ENC_ = 512, ATT_ = 512;
constexpr int H_ = 512, E_ = 256, V_ = 10000, G4_ = 2048;

__device__ __forceinline__ float fast_tanhf(float x) {
    x = fminf(fmaxf(x, -15.f), 15.f);
    float e = __expf(2.f * x);
    return (e - 1.f) / (e + 1.f);
}
__device__ __forceinline__ float fast_sigf(float x) {
    x = fminf(fmaxf(x, -30.f), 30.f);
    return 1.f / (1.f + __expf(-x));
}

// ---------------- embeds_all[s*128+b][e] = emb[tok]+pos_emb[s] ----------------
__global__ __launch_bounds__(256) void k_embed(const int* __restrict__ dec,
                                               const float* __restrict__ emb,
                                               const float* __restrict__ pose,
                                               float* __restrict__ embeds) {
    int bx = blockIdx.x;           // = s*128 + b
    int s = bx >> 7, b = bx & 127;
    int e = threadIdx.x;           // E_ == 256
    int tok = dec[b * S_ + s];
    embeds[bx * E_ + e] = emb[tok * E_ + e] + pose[s * E_ + e];
}

// ---------------- mean_enc -> h0 (Hall slot 0), c0 ----------------
__global__ __launch_bounds__(256) void k_init(const float* __restrict__ enc,
                                              const float* __restrict__ ihw, const float* __restrict__ ihb,
                                              const float* __restrict__ icw, const float* __restrict__ icb,
                                              float* __restrict__ Hall, float* __restrict__ cbuf) {
    __shared__ float mean[ENC_];
    int b = blockIdx.x, t = threadIdx.x;
    for (int d = t; d < ENC_; d += 256) {
        float sum = 0.f;
        for (int n = 0; n < NF_; ++n) sum += enc[(b * NF_ + n) * ENC_ + d];
        mean[d] = sum * (1.f / NF_);
    }
    __syncthreads();
    for (int j = t; j < H_; j += 256) {
        float ah = 0.f, ac = 0.f;
        const float4* wh = (const float4*)&ihw[j * ENC_];
        const float4* wc = (const float4*)&icw[j * ENC_];
        for (int d4 = 0; d4 < ENC_ / 4; ++d4) {
            float4 m4 = *(const float4*)&mean[d4 * 4];
            float4 h4 = wh[d4], c4 = wc[d4];
            ah += m4.x * h4.x + m4.y * h4.y + m4.z * h4.z + m4.w * h4.w;
            ac += m4.x * c4.x + m4.y * c4.y + m4.z * c4.z + m4.w * c4.w;
        }
        Hall[b * H_ + j] = ah + ihb[j];
        cbuf[b * H_ + j] = ac + icb[j];
    }
}

// ---------------- 128x128 tiled f32 GEMM: C[m,n] = A[m,:].B[n,:] + bias ----------------
// A: [M,K] row-major (lda), Bm: [N,K] row-major (ldb). REMAP: row m=s*128+b -> b*25+s.
template<bool REMAP>
__global__ __launch_bounds__(256) void k_gemm128(
    const float* __restrict__ A, int lda,
    const float* __restrict__ Bm, int ldb,
    const float* __restrict__ bias1, const float* __restrict__ bias2,
    float* __restrict__ C, int ldc, int N, int K) {
    __shared__ float As[16][132];
    __shared__ float Bs[16][132];
    int tid = threadIdx.x;
    int m0 = blockIdx.x * 128, n0 = blockIdx.y * 128;
    int tm = (tid >> 4) * 8, tn = (tid & 15) * 8;
    float acc[8][8] = {};
    for (int k0 = 0; k0 < K; k0 += 16) {
#pragma unroll
        for (int it = 0; it < 2; ++it) {
            int q = tid + it * 256;
            int row = q >> 2, kq = (q & 3) << 2;
            float4 av = *(const float4*)&A[(m0 + row) * lda + k0 + kq];
            As[kq + 0][row] = av.x; As[kq + 1][row] = av.y;
            As[kq + 2][row] = av.z; As[kq + 3][row] = av.w;
            float4 bv = make_float4(0.f, 0.f, 0.f, 0.f);
            if (n0 + row < N) bv = *(const float4*)&Bm[(n0 + row) * ldb + k0 + kq];
            Bs[kq + 0][row] = bv.x; Bs[kq + 1][row] = bv.y;
            Bs[kq + 2][row] = bv.z; Bs[kq + 3][row] = bv.w;
        }
        __syncthreads();
#pragma unroll
        for (int kk = 0; kk < 16; ++kk) {
            float4 a0 = *(const float4*)&As[kk][tm];
            float4 a1 = *(const float4*)&As[kk][tm + 4];
            float4 b0 = *(const float4*)&Bs[kk][tn];
            float4 b1 = *(const float4*)&Bs[kk][tn + 4];
            float a[8] = {a0.x, a0.y, a0.z, a0.w, a1.x, a1.y, a1.z, a1.w};
            float bb[8] = {b0.x, b0.y, b0.z, b0.w, b1.x, b1.y, b1.z, b1.w};
#pragma unroll
            for (int i = 0; i < 8; ++i)
#pragma unroll
                for (int j = 0; j < 8; ++j) acc[i][j] += a[i] * bb[j];
        }
        __syncthreads();
    }
#pragma unroll
    for (int i = 0; i < 8; ++i) {
        int m = m0 + tm + i;
        int orow = REMAP ? ((m & 127) * S_ + (m >> 7)) : m;
#pragma unroll
        for (int j = 0; j < 8; ++j) {
            int n = n0 + tn + j;
            if (n < N) {
                float v = acc[i][j];
                if (bias1) v += bias1[n];
                if (bias2) v += bias2[n];
                C[orow * ldc + n] = v;
            }
        }
    }
}

// ---------------- 64x64 split-K f32 GEMM (M==128 multiple of 64, exact N), partials ----------------
__global__ __launch_bounds__(256) void k_gemm64(
    const float* __restrict__ A, int lda,
    const float* __restrict__ Bm, int ldb,
    float* __restrict__ Cpart, int N, int Ktot) {
    __shared__ float As[16][68];
    __shared__ float Bs[16][68];
    int tid = threadIdx.x;
    int m0 = blockIdx.x * 64, n0 = blockIdx.y * 64;
    int kchunk = Ktot / gridDim.z;
    int kbeg = blockIdx.z * kchunk;
    int tm = (tid >> 4) * 4, tn = (tid & 15) * 4;
    float acc[4][4] = {};
    for (int k0 = kbeg; k0 < kbeg + kchunk; k0 += 16) {
        int row = tid >> 2, kq = (tid & 3) << 2;
        float4 av = *(const float4*)&A[(m0 + row) * lda + k0 + kq];
        As[kq + 0][row] = av.x; As[kq + 1][row] = av.y;
        As[kq + 2][row] = av.z; As[kq + 3][row] = av.w;
        float4 bv = *(const float4*)&Bm[(n0 + row) * ldb + k0 + kq];
        Bs[kq + 0][row] = bv.x; Bs[kq + 1][row] = bv.y;
        Bs[kq + 2][row] = bv.z; Bs[kq + 3][row] = bv.w;
        __syncthreads();
#pragma unroll
        for (int kk = 0; kk < 16; ++kk) {
            float4 a4 = *(const float4*)&As[kk][tm];
            float4 b4 = *(const float4*)&Bs[kk][tn];
            float a[4] = {a4.x, a4.y, a4.z, a4.w};
            float bb[4] = {b4.x, b4.y, b4.z, b4.w};
#pragma unroll
            for (int i = 0; i < 4; ++i)
#pragma unroll
                for (int j = 0; j < 4; ++j) acc[i][j] += a[i] * bb[j];
        }
        __syncthreads();
    }
    int zoff = blockIdx.z * (128 * N);
#pragma unroll
    for (int i = 0; i < 4; ++i) {
        int m = m0 + tm + i;
#pragma unroll
        for (int j = 0; j < 4; ++j) Cpart[zoff + m * N + n0 + tn + j] = acc[i][j];
    }
}

// ---------------- per-step attention: scores -> softmax -> context ----------------
__global__ __launch_bounds__(256) void k_attn(
    const float* __restrict__ u_hs, const float* __restrict__ enc,
    const float* __restrict__ wah_part, const float* __restrict__ Wb,
    const float* __restrict__ Aw, const float* __restrict__ Ab,
    float* __restrict__ ctx, float* __restrict__ alphas, int s) {
    __shared__ float wah[ATT_];
    __shared__ float aw[ATT_];
    __shared__ float sc[224];
    __shared__ float red[256];
    int b = blockIdx.x, t = threadIdx.x;
    for (int d = t; d < ATT_; d += 256) {
        float v = Wb[d];
#pragma unroll
        for (int z = 0; z < 4; ++z) v += wah_part[(z * B_ + b) * ATT_ + d];
        wah[d] = v;
        aw[d] = Aw[d];
    }
    __syncthreads();
    int wave = t >> 6, lane = t & 63;
    for (int n = wave; n < NF_; n += 4) {
        const float* up = &u_hs[(b * NF_ + n) * ATT_ + lane * 8];
        float4 u0 = *(const float4*)up;
        float4 u1 = *(const float4*)(up + 4);
        int a0 = lane * 8;
        float acc = fast_tanhf(u0.x + wah[a0 + 0]) * aw[a0 + 0]
                  + fast_tanhf(u0.y + wah[a0 + 1]) * aw[a0 + 1]
                  + fast_tanhf(u0.z + wah[a0 + 2]) * aw[a0 + 2]
                  + fast_tanhf(u0.w + wah[a0 + 3]) * aw[a0 + 3]
                  + fast_tanhf(u1.x + wah[a0 + 4]) * aw[a0 + 4]
                  + fast_tanhf(u1.y + wah[a0 + 5]) * aw[a0 + 5]
                  + fast_tanhf(u1.z + wah[a0 + 6]) * aw[a0 + 6]
                  + fast_tanhf(u1.w + wah[a0 + 7]) * aw[a0 + 7];
#pragma unroll
        for (int off = 32; off > 0; off >>= 1) acc += __shfl_xor(acc, off);
        if (lane == 0) sc[n] = acc + Ab[0];
    }
    __syncthreads();
    // softmax over NF_=196
    red[t] = (t < NF_) ? sc[t] : -1e30f;
    __syncthreads();
    for (int off = 128; off > 0; off >>= 1) {
        if (t < off) red[t] = fmaxf(red[t], red[t + off]);
        __syncthreads();
    }
    float mx = red[0];
    __syncthreads();
    float e = (t < NF_) ? __expf(sc[t] - mx) : 0.f;
    red[t] = e;
    __syncthreads();
    for (int off = 128; off > 0; off >>= 1) {
        if (t < off) red[t] += red[t + off];
        __syncthreads();
    }
    float inv = 1.f / red[0];
    __syncthreads();
    if (t < NF_) {
        float a = e * inv;
        sc[t] = a;
        alphas[(b * S_ + s) * NF_ + t] = a;
    }
    __syncthreads();
    // context[b][d] = sum_n alpha[n]*enc[b][n][d]
    float c0 = 0.f, c1 = 0.f;
    for (int n = 0; n < NF_; ++n) {
        float a = sc[n];
        c0 += a * enc[(b * NF_ + n) * ENC_ + t];
        c1 += a * enc[(b * NF_ + n) * ENC_ + t + 256];
    }
    ctx[b * ENC_ + t] = c0;
    ctx[b * ENC_ + t + 256] = c1;
}

// ---------------- LSTM pointwise: sum partials + gates_pre, update c, write h ----------------
__global__ __launch_bounds__(256) void k_lstm(
    const float* __restrict__ gates_pre, const float* __restrict__ gpart,
    float* __restrict__ cbuf, float* __restrict__ Hall, int s) {
    int idx = blockIdx.x * 256 + threadIdx.x;  // 0..65535
    int b = idx >> 9, j = idx & 511;
    float q[4];
#pragma unroll
    for (int g = 0; g < 4; ++g) {
        int n = g * 512 + j;
        float v = gates_pre[(s * B_ + b) * G4_ + n];
#pragma unroll
        for (int p = 0; p < 8; ++p) v += gpart[p * (B_ * G4_) + b * G4_ + n];
        q[g] = v;
    }
    float ig = fast_sigf(q[0]), fg = fast_sigf(q[1]);
    float gg = fast_tanhf(q[2]), og = fast_sigf(q[3]);
    float cn = fg * cbuf[idx] + ig * gg;
    float hn = og * fast_tanhf(cn);
    cbuf[idx] = cn;
    Hall[(s + 1) * (B_ * H_) + idx] = hn;
}

extern "C" void kernel_launch(void* const* d_in, const int* in_sizes, int n_in,
                              void* d_out, int out_size, void* d_ws, size_t ws_size,
                              hipStream_t stream) {
    const int*   dec  = (const int*)d_in[0];
    const float* enc  = (const float*)d_in[1];
    const float* emb  = (const float*)d_in[2];
    const float* pose = (const float*)d_in[3];
    const float* Uw   = (const float*)d_in[4];
    const float* Ub   = (const float*)d_in[5];
    const float* Ww   = (const float*)d_in[6];
    const float* Wb   = (const float*)d_in[7];
    const float* Aw   = (const float*)d_in[8];
    const float* Ab   = (const float*)d_in[9];
    const float* ihw  = (const float*)d_in[10];
    const float* ihb  = (const float*)d_in[11];
    const float* icw  = (const float*)d_in[12];
    const float* icb  = (const float*)d_in[13];
    const float* W_ih = (const float*)d_in[14];
    const float* W_hh = (const float*)d_in[15];
    const float* b_ih = (const float*)d_in[16];
    const float* b_hh = (const float*)d_in[17];
    const float* fcw  = (const float*)d_in[18];
    const float* fcb  = (const float*)d_in[19];
    float* out  = (float*)d_out;
    float* wsf  = (float*)d_ws;

    // workspace layout (floats) — total ~97.6 MB
    float* u_hs     = wsf;                        // 25088*512   = 12,845,056
    float* embeds   = u_hs + 12845056;            // 3200*256    =    819,200
    float* gatespre = embeds + 819200;            // 3200*2048   =  6,553,600
    float* Hall     = gatespre + 6553600;         // 26*128*512  =  1,703,936
    float* cbuf     = Hall + 1703936;             // 128*512     =     65,536
    float* wahp     = cbuf + 65536;               // 4*128*512   =    262,144
    float* ctx      = wahp + 262144;              // 128*512     =     65,536
    float* gpart    = ctx + 65536;                // 8*128*2048  =  2,097,152

    // loop-invariant precomputes
    k_embed<<<S_ * B_, 256, 0, stream>>>(dec, emb, pose, embeds);
    k_init<<<B_, 256, 0, stream>>>(enc, ihw, ihb, icw, icb, Hall, cbuf);
    // u_hs = enc @ Uw^T + Ub : [25088,512]
    k_gemm128<false><<<dim3(196, 4), 256, 0, stream>>>(enc, ENC_, Uw, ENC_, Ub, nullptr,
                                                       u_hs, ATT_, ATT_, ENC_);
    // gates_pre = embeds @ W_ih[:, :256]^T + b_ih + b_hh : [3200,2048]
    k_gemm128<false><<<dim3(25, 16), 256, 0, stream>>>(embeds, E_, W_ih, E_ + ENC_, b_ih, b_hh,
                                                       gatespre, G4_, G4_, E_);

    for (int s = 0; s < S_; ++s) {
        const float* h = Hall + s * (B_ * H_);
        // w_ah partials = h @ Ww^T (split-K 4)
        k_gemm64<<<dim3(2, 8, 4), 256, 0, stream>>>(h, H_, Ww, H_, wahp, ATT_, H_);
        // scores -> softmax -> alphas + context
        k_attn<<<B_, 256, 0, stream>>>(u_hs, enc, wahp, Wb, Aw, Ab, ctx, out + 32000000, s);
        // gates partials: ctx @ W_ih[:,256:]^T (slots 0-3), h @ W_hh^T (slots 4-7)
        k_gemm64<<<dim3(2, 32, 4), 256, 0, stream>>>(ctx, ENC_, W_ih + E_, E_ + ENC_, gpart, G4_, ENC_);
        k_gemm64<<<dim3(2, 32, 4), 256, 0, stream>>>(h, H_, W_hh, H_, gpart + 4 * B_ * G4_, G4_, H_);
        // LSTM pointwise -> c, Hall[s+1]
        k_lstm<<<256, 256, 0, stream>>>(gatespre, gpart, cbuf, Hall, s);
    }

    // outs = Hall[1..25] @ fcn_w^T + fcn_b, stored as [B,S,V]
    k_gemm128<true><<<dim3(25, 79), 256, 0, stream>>>(Hall + B_ * H_, H_, fcw, H_, fcb, nullptr,
                                                      out, V_, V_, H_);
}